// Round 6
// baseline (65609.546 us; speedup 1.0000x reference)
//
#include <hip/hip_runtime.h>
#include <hip/hip_bf16.h>
#include <cstdint>
#include <cstddef>

#define HID   64
#define G3    192
#define LSEQ  4096
#define NCLS  230

using u16 = unsigned short;
using u32 = unsigned int;

__device__ __forceinline__ float bf2f(u16 u) {
    return __uint_as_float(((u32)u) << 16);
}
// f32 -> bf16 bits, round-to-nearest-even (no dependence on __hip_bfloat16 layout)
__device__ __forceinline__ u16 f2bf(float f) {
    u32 x = __float_as_uint(f);
    u32 lsb = (x >> 16) & 1u;
    x += 0x7fffu + lsb;
    return (u16)(x >> 16);
}

// ---------------------------------------------------------------------------
// Fully-fused recurrent layer: input projection + recurrence in one kernel.
// One workgroup per (batch-in-chunk, direction); 192 threads, thread g owns
// gate row g (r: 0-63, z: 64-127, n: 128-191). Input-proj weights (128 f32)
// and hidden weights (64 f32) live in VGPRs; x_in staged in LDS,
// double-buffered, global prefetch 2 steps ahead.
// MODE 0: layer 0 (scalar f32 input), writes lout
// MODE 1: middle layer (128-wide input), writes lout
// MODE 2: last layer, writes only last-timestep state to lastb (f32)
// HALF: activation ping-pong buffers stored as bf16 (tiny-ws fallback only)
// ---------------------------------------------------------------------------
template<int MODE, bool HALF>
__global__ __launch_bounds__(192) void rec_fused(
    const void* __restrict__ xin,   // MODE0: [Bc][L] f32; else [Bc][L][128] f32|bf16
    const float* __restrict__ wih,  // MODE0: [2][192]; else [2][192][128] f32
    const float* __restrict__ bih,  // [2][192] f32 (this layer)
    const float* __restrict__ whh,  // [2][192][64] f32 (this layer)
    const float* __restrict__ bhh,  // [2][192] f32 (this layer)
    void* __restrict__ lout,        // [Bc][L][128] f32|bf16 (MODE<=1)
    float* __restrict__ lastb,      // [B][128] f32 (MODE==2)
    int bbase)                      // global batch offset of this chunk
{
    const int bc = blockIdx.x >> 1;
    const int d  = blockIdx.x & 1;
    const int g  = threadIdx.x;

    __shared__ float hs[HID];
    __shared__ float rbuf[HID];
    __shared__ float zbuf[HID];
    __shared__ float xs[2][128];

    // hidden weights: 64 f32 -> regs
    float wh[HID];
    {
        const float4* p = (const float4*)(whh + (size_t)(d * G3 + g) * HID);
        #pragma unroll
        for (int i = 0; i < 16; ++i) {
            float4 v = p[i];
            wh[4*i+0] = v.x; wh[4*i+1] = v.y; wh[4*i+2] = v.z; wh[4*i+3] = v.w;
        }
    }
    const float bh = bhh[d * G3 + g];
    const float bi = bih[d * G3 + g];

    // input weights
    float wi[128];              // MODE>=1
    float w0 = 0.f;             // MODE==0
    const float* xp = nullptr;  // MODE==0
    if (MODE == 0) {
        w0 = wih[d * G3 + g];
        xp = (const float*)xin + (size_t)bc * LSEQ;
    } else {
        const float4* p = (const float4*)(wih + (size_t)(d * G3 + g) * 128);
        #pragma unroll
        for (int i = 0; i < 32; ++i) {
            float4 v = p[i];
            wi[4*i+0] = v.x; wi[4*i+1] = v.y; wi[4*i+2] = v.z; wi[4*i+3] = v.w;
        }
    }

    // per-element activation load (f32 or bf16 buffer)
    auto xld = [&](int p, int k) -> float {
        const size_t idx = ((size_t)bc * LSEQ + p) * 128 + k;
        if (HALF) return bf2f(((const u16*)xin)[idx]);
        return ((const float*)xin)[idx];
    };

    if (g < HID) hs[g] = 0.f;

    float pf = 0.f;
    float c0 = 0.f, c1 = 0.f;
    if (MODE == 0) {
        c0 = xp[d ? (LSEQ - 1) : 0];
        c1 = xp[d ? (LSEQ - 2) : 1];
    } else if (g < 128) {
        xs[0][g] = xld(d ? (LSEQ - 1) : 0, g);
        pf       = xld(d ? (LSEQ - 2) : 1, g);
    }
    __syncthreads();

    for (int t = 0; t < LSEQ; ++t) {
        const int p = d ? (LSEQ - 1 - t) : t;

        // stage next input into the other LDS buffer; prefetch t+2 from global
        float c2 = 0.f;
        if (MODE == 0) {
            if (t + 2 < LSEQ) c2 = xp[d ? (LSEQ - 3 - t) : (t + 2)];
        } else if (g < 128) {
            if (t + 1 < LSEQ) xs[(t + 1) & 1][g] = pf;
            if (t + 2 < LSEQ) pf = xld(d ? (LSEQ - 3 - t) : (t + 2), g);
        }

        // hidden matvec (broadcast LDS reads)
        float a0 = 0.f, a1 = 0.f, a2 = 0.f, a3 = 0.f;
        {
            const float4* h4 = (const float4*)hs;
            #pragma unroll
            for (int i = 0; i < 16; ++i) {
                float4 hv = h4[i];
                a0 = fmaf(wh[4*i+0], hv.x, a0);
                a1 = fmaf(wh[4*i+1], hv.y, a1);
                a2 = fmaf(wh[4*i+2], hv.z, a2);
                a3 = fmaf(wh[4*i+3], hv.w, a3);
            }
        }
        const float gh = (a0 + a1) + (a2 + a3) + bh;

        // input projection
        float gxv;
        if (MODE == 0) {
            gxv = fmaf(w0, c0, bi);
        } else {
            float b0 = 0.f, b1 = 0.f, b2 = 0.f, b3 = 0.f;
            const float4* x4 = (const float4*)xs[t & 1];
            #pragma unroll
            for (int i = 0; i < 32; ++i) {
                float4 xv = x4[i];
                b0 = fmaf(wi[4*i+0], xv.x, b0);
                b1 = fmaf(wi[4*i+1], xv.y, b1);
                b2 = fmaf(wi[4*i+2], xv.z, b2);
                b3 = fmaf(wi[4*i+3], xv.w, b3);
            }
            gxv = (b0 + b1) + (b2 + b3) + bi;
        }

        if (g < 128) {
            float s = 1.f / (1.f + __expf(-(gxv + gh)));   // r, z gates
            if (g < HID) rbuf[g] = s;
            else         zbuf[g - HID] = s;
        }
        __syncthreads();
        if (g >= 128) {
            const int j = g - 128;
            float y = gxv + rbuf[j] * gh;
            y = fminf(fmaxf(y, -15.f), 15.f);
            const float e = __expf(-2.f * y);
            const float n = (1.f - e) / (1.f + e);         // tanh(y)
            const float z = zbuf[j];
            const float hn = fmaf(z, hs[j] - n, n);        // (1-z)*n + z*h
            hs[j] = hn;
            if (MODE <= 1) {
                const size_t oi = ((size_t)bc * LSEQ + p) * 128 + d * HID + j;
                if (HALF) ((u16*)lout)[oi] = f2bf(hn);
                else      ((float*)lout)[oi] = hn;
            } else {
                if (p == LSEQ - 1)
                    lastb[(size_t)(bbase + bc) * 128 + d * HID + j] = hn;
            }
        }
        __syncthreads();
        // last layer, reverse dir: only t==0 (p==L-1) feeds the FC — stop.
        if (MODE == 2 && d == 1) return;
        c0 = c1; c1 = c2;
    }
}

// ---------------------------------------------------------------------------
// FC: out[b][c] = sum_k last[b][k] * fc_w[c][k] + fc_b[c]   (all f32)
// ---------------------------------------------------------------------------
__global__ __launch_bounds__(256) void fc_kernel(
    const float* __restrict__ lastb,
    const float* __restrict__ fcw,
    const float* __restrict__ fcb,
    float* __restrict__ out)
{
    __shared__ float ls[128];
    const int b = blockIdx.x;
    const int tid = threadIdx.x;
    if (tid < 128) ls[tid] = lastb[b * 128 + tid];
    __syncthreads();
    if (tid < NCLS) {
        float acc = fcb[tid];
        const float4* w4 = (const float4*)(fcw + (size_t)tid * 128);
        const float4* l4 = (const float4*)ls;
        #pragma unroll
        for (int i = 0; i < 32; ++i) {
            float4 wv = w4[i];
            float4 lv = l4[i];
            acc += wv.x*lv.x + wv.y*lv.y + wv.z*lv.z + wv.w*lv.w;
        }
        out[b * NCLS + tid] = acc;
    }
}

// ---------------------------------------------------------------------------
// Workspace (ADAPTIVE — never exceeds ws_size):
//   [0, 65536)                lastb [128][128] f32
//   [65536, ...)              bufA, bufB: [Bc][4096][128] each, f32 (or bf16
//                             in the tiny-ws fallback).
// Bc = largest of {128,...,1} fitting in ws_size with f32 buffers; if none
// fits, retry ladder with bf16 buffers; if still none, do nothing (fails
// validation safely instead of faulting). ws_size is constant -> capture-safe.
// ---------------------------------------------------------------------------
extern "C" void kernel_launch(void* const* d_in, const int* in_sizes, int n_in,
                              void* d_out, int out_size, void* d_ws, size_t ws_size,
                              hipStream_t stream)
{
    if (n_in < 8) return;
    const float* x    = (const float*)d_in[0];   // [128][1][4096]
    const float* wih0 = (const float*)d_in[1];   // [2][192][1]
    const float* wih  = (const float*)d_in[2];   // [3][2][192][128]
    const float* whh  = (const float*)d_in[3];   // [4][2][192][64]
    const float* bih  = (const float*)d_in[4];   // [4][2][192]
    const float* bhh  = (const float*)d_in[5];   // [4][2][192]
    const float* fcw  = (const float*)d_in[6];   // [230][128]
    const float* fcb  = (const float*)d_in[7];   // [230]
    float* out = (float*)d_out;

    char* ws = (char*)d_ws;
    float* lastb = (float*)ws;
    const size_t seqbytes_f32 = (size_t)LSEQ * 128 * 4;   // per batch elem
    const size_t seqbytes_b16 = (size_t)LSEQ * 128 * 2;

    int Bc = 0; bool half = false;
    for (int c = 128; c >= 1; c >>= 1)
        if (65536ull + 2ull * c * seqbytes_f32 <= ws_size) { Bc = c; break; }
    if (Bc == 0) {
        for (int c = 128; c >= 1; c >>= 1)
            if (65536ull + 2ull * c * seqbytes_b16 <= ws_size) { Bc = c; half = true; break; }
    }
    if (Bc == 0) return;

    void* bufA = (void*)(ws + 65536);
    void* bufB = (void*)(ws + 65536 + (size_t)Bc * (half ? seqbytes_b16 : seqbytes_f32));

    for (int bbase = 0; bbase < 128; bbase += Bc) {
        const float* xc = x + (size_t)bbase * LSEQ;
        if (!half) {
            rec_fused<0,false><<<2*Bc, 192, 0, stream>>>(xc, wih0, bih, whh, bhh, bufA, nullptr, bbase);
            rec_fused<1,false><<<2*Bc, 192, 0, stream>>>(bufA, wih,           bih+384,  whh+24576,   bhh+384,  bufB, nullptr, bbase);
            rec_fused<1,false><<<2*Bc, 192, 0, stream>>>(bufB, wih+49152,     bih+768,  whh+2*24576, bhh+768,  bufA, nullptr, bbase);
            rec_fused<2,false><<<2*Bc, 192, 0, stream>>>(bufA, wih+2*49152,   bih+1152, whh+3*24576, bhh+1152, nullptr, lastb, bbase);
        } else {
            rec_fused<0,true><<<2*Bc, 192, 0, stream>>>(xc, wih0, bih, whh, bhh, bufA, nullptr, bbase);
            rec_fused<1,true><<<2*Bc, 192, 0, stream>>>(bufA, wih,           bih+384,  whh+24576,   bhh+384,  bufB, nullptr, bbase);
            rec_fused<1,true><<<2*Bc, 192, 0, stream>>>(bufB, wih+49152,     bih+768,  whh+2*24576, bhh+768,  bufA, nullptr, bbase);
            rec_fused<2,true><<<2*Bc, 192, 0, stream>>>(bufA, wih+2*49152,   bih+1152, whh+3*24576, bhh+1152, nullptr, lastb, bbase);
        }
    }
    fc_kernel<<<128, 256, 0, stream>>>(lastb, fcw, fcb, out);
}

// Round 7
// 64714.844 us; speedup vs baseline: 1.0138x; 1.0138x over previous
//
#include <hip/hip_runtime.h>
#include <hip/hip_bf16.h>
#include <cstdint>
#include <cstddef>

#define HID   64
#define G3    192
#define LSEQ  4096
#define NCLS  230

using u16 = unsigned short;
using u32 = unsigned int;

__device__ __forceinline__ float bf2f(u16 u) {
    return __uint_as_float(((u32)u) << 16);
}
// f32 -> bf16 bits, round-to-nearest-even (no dependence on __hip_bfloat16 layout)
__device__ __forceinline__ u16 f2bf(float f) {
    u32 x = __float_as_uint(f);
    u32 lsb = (x >> 16) & 1u;
    x += 0x7fffu + lsb;
    return (u16)(x >> 16);
}

// ---------------------------------------------------------------------------
// Fully-fused recurrent layer: input projection + recurrence in one kernel.
// One workgroup per (batch-in-chunk, direction); 192 threads, thread g owns
// gate row g (r: 0-63, z: 64-127, n: 128-191).
//
// __launch_bounds__(192, 1): CRITICAL. The kernel keeps 192 f32 weights per
// thread (wi[128] + wh[64]) in VGPRs. With the default occupancy target the
// compiler capped allocation at 116 VGPRs and spilled wi[] to scratch —
// measured r6: VALUBusy 5.9%, 35 ms/dispatch. We run 1 block/CU (serial
// scan, no extra parallelism exists), so max VGPR allocation is free.
//
// MODE 0: layer 0 (scalar f32 input), writes lout
// MODE 1: middle layer (128-wide input), writes lout
// MODE 2: last layer, writes only last-timestep state to lastb (f32)
// HALF: activation ping-pong buffers stored as bf16 (tiny-ws fallback only)
// ---------------------------------------------------------------------------
template<int MODE, bool HALF>
__global__ __launch_bounds__(192, 1) void rec_fused(
    const void* __restrict__ xin,   // MODE0: [Bc][L] f32; else [Bc][L][128] f32|bf16
    const float* __restrict__ wih,  // MODE0: [2][192]; else [2][192][128] f32
    const float* __restrict__ bih,  // [2][192] f32 (this layer)
    const float* __restrict__ whh,  // [2][192][64] f32 (this layer)
    const float* __restrict__ bhh,  // [2][192] f32 (this layer)
    void* __restrict__ lout,        // [Bc][L][128] f32|bf16 (MODE<=1)
    float* __restrict__ lastb,      // [B][128] f32 (MODE==2)
    int bbase)                      // global batch offset of this chunk
{
    const int bc = blockIdx.x >> 1;
    const int d  = blockIdx.x & 1;
    const int g  = threadIdx.x;

    __shared__ float hs[HID];
    __shared__ float rbuf[HID];
    __shared__ float zbuf[HID];
    __shared__ float xs[2][128];

    // hidden weights: 64 f32 -> regs
    float wh[HID];
    {
        const float4* p = (const float4*)(whh + (size_t)(d * G3 + g) * HID);
        #pragma unroll
        for (int i = 0; i < 16; ++i) {
            float4 v = p[i];
            wh[4*i+0] = v.x; wh[4*i+1] = v.y; wh[4*i+2] = v.z; wh[4*i+3] = v.w;
        }
    }
    const float bh = bhh[d * G3 + g];
    const float bi = bih[d * G3 + g];

    // input weights
    float wi[128];              // MODE>=1
    float w0 = 0.f;             // MODE==0
    const float* xp = nullptr;  // MODE==0
    if (MODE == 0) {
        w0 = wih[d * G3 + g];
        xp = (const float*)xin + (size_t)bc * LSEQ;
    } else {
        const float4* p = (const float4*)(wih + (size_t)(d * G3 + g) * 128);
        #pragma unroll
        for (int i = 0; i < 32; ++i) {
            float4 v = p[i];
            wi[4*i+0] = v.x; wi[4*i+1] = v.y; wi[4*i+2] = v.z; wi[4*i+3] = v.w;
        }
    }

    // per-element activation load (f32 or bf16 buffer)
    auto xld = [&](int p, int k) -> float {
        const size_t idx = ((size_t)bc * LSEQ + p) * 128 + k;
        if (HALF) return bf2f(((const u16*)xin)[idx]);
        return ((const float*)xin)[idx];
    };

    if (g < HID) hs[g] = 0.f;

    float pf = 0.f;
    float c0 = 0.f, c1 = 0.f;
    if (MODE == 0) {
        c0 = xp[d ? (LSEQ - 1) : 0];
        c1 = xp[d ? (LSEQ - 2) : 1];
    } else if (g < 128) {
        xs[0][g] = xld(d ? (LSEQ - 1) : 0, g);
        pf       = xld(d ? (LSEQ - 2) : 1, g);
    }
    __syncthreads();

    for (int t = 0; t < LSEQ; ++t) {
        const int p = d ? (LSEQ - 1 - t) : t;

        // stage next input into the other LDS buffer; prefetch t+2 from global
        float c2 = 0.f;
        if (MODE == 0) {
            if (t + 2 < LSEQ) c2 = xp[d ? (LSEQ - 3 - t) : (t + 2)];
        } else if (g < 128) {
            if (t + 1 < LSEQ) xs[(t + 1) & 1][g] = pf;
            if (t + 2 < LSEQ) pf = xld(d ? (LSEQ - 3 - t) : (t + 2), g);
        }

        // hidden matvec (broadcast LDS reads)
        float a0 = 0.f, a1 = 0.f, a2 = 0.f, a3 = 0.f;
        {
            const float4* h4 = (const float4*)hs;
            #pragma unroll
            for (int i = 0; i < 16; ++i) {
                float4 hv = h4[i];
                a0 = fmaf(wh[4*i+0], hv.x, a0);
                a1 = fmaf(wh[4*i+1], hv.y, a1);
                a2 = fmaf(wh[4*i+2], hv.z, a2);
                a3 = fmaf(wh[4*i+3], hv.w, a3);
            }
        }
        const float gh = (a0 + a1) + (a2 + a3) + bh;

        // input projection
        float gxv;
        if (MODE == 0) {
            gxv = fmaf(w0, c0, bi);
        } else {
            float b0 = 0.f, b1 = 0.f, b2 = 0.f, b3 = 0.f;
            const float4* x4 = (const float4*)xs[t & 1];
            #pragma unroll
            for (int i = 0; i < 32; ++i) {
                float4 xv = x4[i];
                b0 = fmaf(wi[4*i+0], xv.x, b0);
                b1 = fmaf(wi[4*i+1], xv.y, b1);
                b2 = fmaf(wi[4*i+2], xv.z, b2);
                b3 = fmaf(wi[4*i+3], xv.w, b3);
            }
            gxv = (b0 + b1) + (b2 + b3) + bi;
        }

        if (g < 128) {
            float s = 1.f / (1.f + __expf(-(gxv + gh)));   // r, z gates
            if (g < HID) rbuf[g] = s;
            else         zbuf[g - HID] = s;
        }
        __syncthreads();
        if (g >= 128) {
            const int j = g - 128;
            float y = gxv + rbuf[j] * gh;
            y = fminf(fmaxf(y, -15.f), 15.f);
            const float e = __expf(-2.f * y);
            const float n = (1.f - e) / (1.f + e);         // tanh(y)
            const float z = zbuf[j];
            const float hn = fmaf(z, hs[j] - n, n);        // (1-z)*n + z*h
            hs[j] = hn;
            if (MODE <= 1) {
                const size_t oi = ((size_t)bc * LSEQ + p) * 128 + d * HID + j;
                if (HALF) ((u16*)lout)[oi] = f2bf(hn);
                else      ((float*)lout)[oi] = hn;
            } else {
                if (p == LSEQ - 1)
                    lastb[(size_t)(bbase + bc) * 128 + d * HID + j] = hn;
            }
        }
        __syncthreads();
        // last layer, reverse dir: only t==0 (p==L-1) feeds the FC — stop.
        if (MODE == 2 && d == 1) return;
        c0 = c1; c1 = c2;
    }
}

// ---------------------------------------------------------------------------
// FC: out[b][c] = sum_k last[b][k] * fc_w[c][k] + fc_b[c]   (all f32)
// ---------------------------------------------------------------------------
__global__ __launch_bounds__(256) void fc_kernel(
    const float* __restrict__ lastb,
    const float* __restrict__ fcw,
    const float* __restrict__ fcb,
    float* __restrict__ out)
{
    __shared__ float ls[128];
    const int b = blockIdx.x;
    const int tid = threadIdx.x;
    if (tid < 128) ls[tid] = lastb[b * 128 + tid];
    __syncthreads();
    if (tid < NCLS) {
        float acc = fcb[tid];
        const float4* w4 = (const float4*)(fcw + (size_t)tid * 128);
        const float4* l4 = (const float4*)ls;
        #pragma unroll
        for (int i = 0; i < 32; ++i) {
            float4 wv = w4[i];
            float4 lv = l4[i];
            acc += wv.x*lv.x + wv.y*lv.y + wv.z*lv.z + wv.w*lv.w;
        }
        out[b * NCLS + tid] = acc;
    }
}

// ---------------------------------------------------------------------------
// Workspace (ADAPTIVE — never exceeds ws_size):
//   [0, 65536)                lastb [128][128] f32
//   [65536, ...)              bufA, bufB: [Bc][4096][128] each, f32 (or bf16
//                             in the tiny-ws fallback).
// Bc = largest of {128,...,1} fitting in ws_size with f32 buffers; if none
// fits, retry ladder with bf16 buffers; if still none, do nothing (fails
// validation safely instead of faulting). ws_size is constant -> capture-safe.
// ---------------------------------------------------------------------------
extern "C" void kernel_launch(void* const* d_in, const int* in_sizes, int n_in,
                              void* d_out, int out_size, void* d_ws, size_t ws_size,
                              hipStream_t stream)
{
    if (n_in < 8) return;
    const float* x    = (const float*)d_in[0];   // [128][1][4096]
    const float* wih0 = (const float*)d_in[1];   // [2][192][1]
    const float* wih  = (const float*)d_in[2];   // [3][2][192][128]
    const float* whh  = (const float*)d_in[3];   // [4][2][192][64]
    const float* bih  = (const float*)d_in[4];   // [4][2][192]
    const float* bhh  = (const float*)d_in[5];   // [4][2][192]
    const float* fcw  = (const float*)d_in[6];   // [230][128]
    const float* fcb  = (const float*)d_in[7];   // [230]
    float* out = (float*)d_out;

    char* ws = (char*)d_ws;
    float* lastb = (float*)ws;
    const size_t seqbytes_f32 = (size_t)LSEQ * 128 * 4;   // per batch elem
    const size_t seqbytes_b16 = (size_t)LSEQ * 128 * 2;

    int Bc = 0; bool half = false;
    for (int c = 128; c >= 1; c >>= 1)
        if (65536ull + 2ull * c * seqbytes_f32 <= ws_size) { Bc = c; break; }
    if (Bc == 0) {
        for (int c = 128; c >= 1; c >>= 1)
            if (65536ull + 2ull * c * seqbytes_b16 <= ws_size) { Bc = c; half = true; break; }
    }
    if (Bc == 0) return;

    void* bufA = (void*)(ws + 65536);
    void* bufB = (void*)(ws + 65536 + (size_t)Bc * (half ? seqbytes_b16 : seqbytes_f32));

    for (int bbase = 0; bbase < 128; bbase += Bc) {
        const float* xc = x + (size_t)bbase * LSEQ;
        if (!half) {
            rec_fused<0,false><<<2*Bc, 192, 0, stream>>>(xc, wih0, bih, whh, bhh, bufA, nullptr, bbase);
            rec_fused<1,false><<<2*Bc, 192, 0, stream>>>(bufA, wih,           bih+384,  whh+24576,   bhh+384,  bufB, nullptr, bbase);
            rec_fused<1,false><<<2*Bc, 192, 0, stream>>>(bufB, wih+49152,     bih+768,  whh+2*24576, bhh+768,  bufA, nullptr, bbase);
            rec_fused<2,false><<<2*Bc, 192, 0, stream>>>(bufA, wih+2*49152,   bih+1152, whh+3*24576, bhh+1152, nullptr, lastb, bbase);
        } else {
            rec_fused<0,true><<<2*Bc, 192, 0, stream>>>(xc, wih0, bih, whh, bhh, bufA, nullptr, bbase);
            rec_fused<1,true><<<2*Bc, 192, 0, stream>>>(bufA, wih,           bih+384,  whh+24576,   bhh+384,  bufB, nullptr, bbase);
            rec_fused<1,true><<<2*Bc, 192, 0, stream>>>(bufB, wih+49152,     bih+768,  whh+2*24576, bhh+768,  bufA, nullptr, bbase);
            rec_fused<2,true><<<2*Bc, 192, 0, stream>>>(bufA, wih+2*49152,   bih+1152, whh+3*24576, bhh+1152, nullptr, lastb, bbase);
        }
    }
    fc_kernel<<<128, 256, 0, stream>>>(lastb, fcw, fcb, out);
}

// Round 8
// 12863.423 us; speedup vs baseline: 5.1005x; 5.0309x over previous
//
#include <hip/hip_runtime.h>
#include <cstdint>
#include <cstddef>

#define HID   64
#define G3    192
#define LSEQ  4096
#define NCLS  230

using u16 = unsigned short;
using u32 = unsigned int;

__device__ __forceinline__ float bf2f(u16 u) {
    return __uint_as_float(((u32)u) << 16);
}
// f32 -> bf16 bits, round-to-nearest-even
__device__ __forceinline__ u16 f2bf(float f) {
    u32 x = __float_as_uint(f);
    x += 0x7fffu + ((x >> 16) & 1u);
    return (u16)(x >> 16);
}

// ---------------------------------------------------------------------------
// Fused GRU layer, 3-way-split rows: 576 threads = 3 groups q of 192 rows g.
//   q=0: holds wi[g][0:64]   -> partial p0 (+bias bih)
//   q=1: holds wi[g][64:128] -> partial p1 (and stages x rows)
//   q=2: holds wh[g][0:64]   -> partial ph (+bias bhh)
// 64 weight-floats per thread: r6 measured that 64-f32 arrays stay VGPR-
// resident at the compiler's 116-reg budget (wh[64] did), while 128+64 got
// demoted to memory (the r6/r7 35 ms/dispatch pathology). 3 barriers/step.
// Activations in/out are bf16 workspace buffers; MODE0 reads f32 x.
// MODE 0: layer 0 (scalar input); MODE 1: middle; MODE 2: last (lastb only).
// ---------------------------------------------------------------------------
template<int MODE>
__global__ __launch_bounds__(576) void rec3(
    const void* __restrict__ xin,   // MODE0: [Bc][L] f32; else [Bc][L][128] bf16
    const float* __restrict__ wih,  // MODE0: [2][192]; else [2][192][128] f32
    const float* __restrict__ bih,  // [2][192] f32 (this layer)
    const float* __restrict__ whh,  // [2][192][64] f32 (this layer)
    const float* __restrict__ bhh,  // [2][192] f32 (this layer)
    u16* __restrict__ lout,         // [Bc][L][128] bf16 (MODE<=1)
    float* __restrict__ lastb,      // [B][128] f32 (MODE==2; aliases d_out)
    int bbase)
{
    const int bc  = blockIdx.x >> 1;
    const int d   = blockIdx.x & 1;
    const int tid = threadIdx.x;
    const int q   = tid / G3;       // 0,1,2 — wave-uniform (192 = 3 waves)
    const int g   = tid % G3;

    __shared__ float xs[2][128];
    __shared__ float hs[HID];
    __shared__ float p0s[G3], p1s[G3], phs[G3];
    __shared__ float rbuf[HID], zbuf[HID];

    float wv[64];
    float w0 = 0.f, bi = 0.f, bh = 0.f;

    if (q == 2) {
        const float4* p = (const float4*)(whh + (size_t)(d * G3 + g) * HID);
        #pragma unroll
        for (int i = 0; i < 16; ++i) {
            float4 v = p[i];
            wv[4*i] = v.x; wv[4*i+1] = v.y; wv[4*i+2] = v.z; wv[4*i+3] = v.w;
        }
        bh = bhh[d * G3 + g];
    } else if (MODE == 0) {
        if (q == 0) { w0 = wih[d * G3 + g]; bi = bih[d * G3 + g]; }
    } else {
        const float4* p = (const float4*)(wih + (size_t)(d * G3 + g) * 128 + q * 64);
        #pragma unroll
        for (int i = 0; i < 16; ++i) {
            float4 v = p[i];
            wv[4*i] = v.x; wv[4*i+1] = v.y; wv[4*i+2] = v.z; wv[4*i+3] = v.w;
        }
        if (q == 0) bi = bih[d * G3 + g];
    }

    if (tid < HID) hs[tid] = 0.f;
    if (MODE == 0 && q == 1) p1s[g] = 0.f;   // never rewritten in MODE0

    const u16*   xb = (const u16*)xin + (size_t)bc * LSEQ * 128;
    const float* xp = (const float*)xin + (size_t)bc * LSEQ;

    auto prow = [&](int t) -> int { return d ? (LSEQ - 1 - t) : t; };

    float c0 = 0.f, c1 = 0.f, c2 = 0.f;
    u32 pf = 0;
    if (MODE == 0) {
        c0 = xp[prow(0)];
        c1 = xp[prow(1)];
    } else if (q == 1 && g < 64) {
        u32 v = ((const u32*)(xb + (size_t)prow(0) * 128))[g];
        xs[0][2*g]   = bf2f((u16)v);
        xs[0][2*g+1] = bf2f((u16)(v >> 16));
        pf = ((const u32*)(xb + (size_t)prow(1) * 128))[g];
    }
    __syncthreads();

    for (int t = 0; t < LSEQ; ++t) {
        const int p = prow(t);

        // ---- phase A: partials + staging ----
        if (MODE == 0) {
            if (q == 0) {
                p0s[g] = fmaf(w0, c0, bi);
                if (t + 2 < LSEQ) c2 = xp[prow(t + 2)];
            } else if (q == 2) {
                float a0=0.f,a1=0.f,a2=0.f,a3=0.f;
                const float4* h4 = (const float4*)hs;
                #pragma unroll
                for (int i = 0; i < 16; ++i) {
                    float4 hv = h4[i];
                    a0 = fmaf(wv[4*i+0], hv.x, a0);
                    a1 = fmaf(wv[4*i+1], hv.y, a1);
                    a2 = fmaf(wv[4*i+2], hv.z, a2);
                    a3 = fmaf(wv[4*i+3], hv.w, a3);
                }
                phs[g] = (a0 + a1) + (a2 + a3) + bh;
            }
        } else {
            if (q == 2) {
                float a0=0.f,a1=0.f,a2=0.f,a3=0.f;
                const float4* h4 = (const float4*)hs;
                #pragma unroll
                for (int i = 0; i < 16; ++i) {
                    float4 hv = h4[i];
                    a0 = fmaf(wv[4*i+0], hv.x, a0);
                    a1 = fmaf(wv[4*i+1], hv.y, a1);
                    a2 = fmaf(wv[4*i+2], hv.z, a2);
                    a3 = fmaf(wv[4*i+3], hv.w, a3);
                }
                phs[g] = (a0 + a1) + (a2 + a3) + bh;
            } else {
                const float4* x4 = (const float4*)(&xs[t & 1][q * 64]);
                float a0=0.f,a1=0.f,a2=0.f,a3=0.f;
                #pragma unroll
                for (int i = 0; i < 16; ++i) {
                    float4 xv = x4[i];
                    a0 = fmaf(wv[4*i+0], xv.x, a0);
                    a1 = fmaf(wv[4*i+1], xv.y, a1);
                    a2 = fmaf(wv[4*i+2], xv.z, a2);
                    a3 = fmaf(wv[4*i+3], xv.w, a3);
                }
                float s = (a0 + a1) + (a2 + a3);
                if (q == 0) p0s[g] = s + bi;
                else        p1s[g] = s;
            }
            if (q == 1 && g < 64) {   // stage next row, prefetch t+2
                if (t + 1 < LSEQ) {
                    xs[(t+1) & 1][2*g]   = bf2f((u16)pf);
                    xs[(t+1) & 1][2*g+1] = bf2f((u16)(pf >> 16));
                }
                if (t + 2 < LSEQ)
                    pf = ((const u32*)(xb + (size_t)prow(t + 2) * 128))[g];
            }
        }
        __syncthreads();

        // ---- phase B: r, z gates (rows 0-127) ----
        if (tid < 128) {
            float a = p0s[tid] + p1s[tid] + phs[tid];
            float s = 1.f / (1.f + __expf(-a));
            if (tid < HID) rbuf[tid] = s;
            else           zbuf[tid - HID] = s;
        }
        __syncthreads();

        // ---- phase C: n gate + h update (rows 128-191) ----
        if (tid >= 128 && tid < 192) {
            const int j = tid - 128;
            const int row = 128 + j;
            float y = p0s[row] + p1s[row] + rbuf[j] * phs[row];
            y = fminf(fmaxf(y, -15.f), 15.f);
            const float e = __expf(-2.f * y);
            const float n = (1.f - e) / (1.f + e);       // tanh(y)
            const float z = zbuf[j];
            const float hn = fmaf(z, hs[j] - n, n);      // (1-z)*n + z*h
            hs[j] = hn;
            if (MODE <= 1) {
                lout[((size_t)bc * LSEQ + p) * 128 + d * HID + j] = f2bf(hn);
            } else if (p == LSEQ - 1) {
                lastb[(size_t)(bbase + bc) * 128 + d * HID + j] = hn;
            }
        }
        __syncthreads();

        // last layer, reverse dir: only t==0 (p==L-1) feeds the FC — stop.
        if (MODE == 2 && d == 1) return;
        if (MODE == 0) { c0 = c1; c1 = c2; }
    }
}

// ---------------------------------------------------------------------------
// FC, SINGLE block: lastb aliases d_out[0:16384], so stage it to LDS before
// overwriting. out[b][c] = sum_k last[b][k]*fc_w[c][k] + fc_b[c].
// ---------------------------------------------------------------------------
__global__ __launch_bounds__(256) void fc_single(
    const float* __restrict__ fcw,
    const float* __restrict__ fcb,
    float* __restrict__ out)           // == lastb
{
    __shared__ float ls[128 * 128];    // 64 KiB
    for (int i = threadIdx.x; i < 128 * 128; i += 256) ls[i] = out[i];
    __syncthreads();
    for (int idx = threadIdx.x; idx < 128 * NCLS; idx += 256) {
        const int b = idx / NCLS;
        const int c = idx % NCLS;
        const float4* w4 = (const float4*)(fcw + (size_t)c * 128);
        const float4* l4 = (const float4*)(ls + b * 128);
        float acc = fcb[c];
        #pragma unroll
        for (int i = 0; i < 32; ++i) {
            float4 w = w4[i], l = l4[i];
            acc += w.x*l.x + w.y*l.y + w.z*l.z + w.w*l.w;
        }
        out[idx] = acc;
    }
}

// ---------------------------------------------------------------------------
// Workspace: ONLY the two bf16 ping-pong activation buffers (lastb lives in
// d_out). Bc = largest chunk with 2*Bc*1MiB <= ws_size. r7 counters showed
// ws_size in [128 MiB+64K, 256 MiB+64K) — bf16 gives Bc=64..128.
// ---------------------------------------------------------------------------
extern "C" void kernel_launch(void* const* d_in, const int* in_sizes, int n_in,
                              void* d_out, int out_size, void* d_ws, size_t ws_size,
                              hipStream_t stream)
{
    if (n_in < 8) return;
    const float* x    = (const float*)d_in[0];   // [128][1][4096]
    const float* wih0 = (const float*)d_in[1];   // [2][192][1]
    const float* wih  = (const float*)d_in[2];   // [3][2][192][128]
    const float* whh  = (const float*)d_in[3];   // [4][2][192][64]
    const float* bih  = (const float*)d_in[4];   // [4][2][192]
    const float* bhh  = (const float*)d_in[5];   // [4][2][192]
    const float* fcw  = (const float*)d_in[6];   // [230][128]
    const float* fcb  = (const float*)d_in[7];   // [230]
    float* out   = (float*)d_out;
    float* lastb = out;                          // first 16384 floats of d_out

    const size_t seqb = (size_t)LSEQ * 128 * 2;  // 1 MiB per batch elem (bf16)
    int Bc = 0;
    {
        const int cand[] = {128, 96, 64, 48, 32, 24, 16, 12, 8, 4, 2, 1};
        for (int i = 0; i < 12; ++i)
            if (2ull * cand[i] * seqb <= ws_size) { Bc = cand[i]; break; }
    }
    if (Bc == 0) return;

    u16* bufA = (u16*)d_ws;
    u16* bufB = bufA + (size_t)Bc * LSEQ * 128;

    for (int bb = 0; bb < 128; ) {
        const int cur = (Bc < 128 - bb) ? Bc : (128 - bb);
        const float* xc = x + (size_t)bb * LSEQ;
        rec3<0><<<2*cur, 576, 0, stream>>>(xc,   wih0,        bih,        whh,          bhh,        bufA, nullptr, bb);
        rec3<1><<<2*cur, 576, 0, stream>>>(bufA, wih,         bih + 384,  whh + 24576,  bhh + 384,  bufB, nullptr, bb);
        rec3<1><<<2*cur, 576, 0, stream>>>(bufB, wih + 49152, bih + 768,  whh + 49152,  bhh + 768,  bufA, nullptr, bb);
        rec3<2><<<2*cur, 576, 0, stream>>>(bufA, wih + 98304, bih + 1152, whh + 73728,  bhh + 1152, nullptr, lastb, bb);
        bb += cur;
    }
    fc_single<<<1, 256, 0, stream>>>(fcw, fcb, out);
}

// Round 9
// 11860.684 us; speedup vs baseline: 5.5317x; 1.0845x over previous
//
#include <hip/hip_runtime.h>
#include <cstdint>
#include <cstddef>

#define HID   64
#define G3    192
#define LSEQ  4096
#define NCLS  230

using u16 = unsigned short;
using u32 = unsigned int;

__device__ __forceinline__ float bf2f(u16 u) {
    return __uint_as_float(((u32)u) << 16);
}
// f32 -> bf16 bits, round-to-nearest-even
__device__ __forceinline__ u16 f2bf(float f) {
    u32 x = __float_as_uint(f);
    x += 0x7fffu + ((x >> 16) & 1u);
    return (u16)(x >> 16);
}

// ---------------------------------------------------------------------------
// Fused GRU layer, 2 barriers/step (r9). 576 threads = 3 groups q of 192:
//   q=0: wi[g][0:64]  -> p0s[g] (+bih)     (MODE0: w0*x+bi)
//   q=1: wi[g][64:128]-> p1s[g]; also stages x rows (double-buffered LDS)
//   q=2: wh[g][0:64]  -> phs[g] (+bhh)
// Phase B (wave 0, threads 0-63): thread j computes r_j, z_j, n_j AND the
// h-update entirely in-registers from the partial arrays — this removed the
// r8 third phase + third barrier + one LDS round trip (r8 measured ~1900
// cyc/step; phases+barriers dominated, matvec is only ~130 cyc).
// 64 weight-floats per thread (r6/r7 measured: 128-f32 arrays get demoted
// to scratch at the compiler's budget; 64 stay resident).
// MODE 0: layer 0 (scalar input); MODE 1: middle; MODE 2: last (lastb only).
// ---------------------------------------------------------------------------
template<int MODE>
__global__ __launch_bounds__(576, 1) void rec2b(
    const void* __restrict__ xin,   // MODE0: [Bc][L] f32; else [Bc][L][128] bf16
    const float* __restrict__ wih,  // MODE0: [2][192]; else [2][192][128] f32
    const float* __restrict__ bih,  // [2][192] f32 (this layer)
    const float* __restrict__ whh,  // [2][192][64] f32 (this layer)
    const float* __restrict__ bhh,  // [2][192] f32 (this layer)
    u16* __restrict__ lout,         // [Bc][L][128] bf16 (MODE<=1)
    float* __restrict__ lastb,      // [B][128] f32 (MODE==2; aliases d_out)
    int bbase)
{
    const int bc  = blockIdx.x >> 1;
    const int d   = blockIdx.x & 1;
    const int tid = threadIdx.x;
    const int q   = tid / G3;       // 0,1,2 — wave-uniform (192 = 3 waves)
    const int g   = tid % G3;

    __shared__ float xs[2][128];
    __shared__ float hs[HID];
    __shared__ float p0s[G3], p1s[G3], phs[G3];

    float wv[64];
    float w0 = 0.f, bi = 0.f, bh = 0.f;

    if (q == 2) {
        const float4* p = (const float4*)(whh + (size_t)(d * G3 + g) * HID);
        #pragma unroll
        for (int i = 0; i < 16; ++i) {
            float4 v = p[i];
            wv[4*i] = v.x; wv[4*i+1] = v.y; wv[4*i+2] = v.z; wv[4*i+3] = v.w;
        }
        bh = bhh[d * G3 + g];
    } else if (MODE == 0) {
        if (q == 0) { w0 = wih[d * G3 + g]; bi = bih[d * G3 + g]; }
    } else {
        const float4* p = (const float4*)(wih + (size_t)(d * G3 + g) * 128 + q * 64);
        #pragma unroll
        for (int i = 0; i < 16; ++i) {
            float4 v = p[i];
            wv[4*i] = v.x; wv[4*i+1] = v.y; wv[4*i+2] = v.z; wv[4*i+3] = v.w;
        }
        if (q == 0) bi = bih[d * G3 + g];
    }

    if (tid < HID) hs[tid] = 0.f;
    if (MODE == 0 && q == 1) p1s[g] = 0.f;   // never rewritten in MODE0

    const u16*   xb = (const u16*)xin + (size_t)bc * LSEQ * 128;
    const float* xp = (const float*)xin + (size_t)bc * LSEQ;

    auto prow = [&](int t) -> int { return d ? (LSEQ - 1 - t) : t; };

    float c0 = 0.f, c1 = 0.f, c2 = 0.f;
    u32 pf = 0;
    if (MODE == 0) {
        c0 = xp[prow(0)];
        c1 = xp[prow(1)];
    } else if (q == 1 && g < 64) {
        u32 v = ((const u32*)(xb + (size_t)prow(0) * 128))[g];
        xs[0][2*g]   = bf2f((u16)v);
        xs[0][2*g+1] = bf2f((u16)(v >> 16));
        pf = ((const u32*)(xb + (size_t)prow(1) * 128))[g];
    }
    __syncthreads();

    for (int t = 0; t < LSEQ; ++t) {
        const int p = prow(t);

        // ---- phase A: partials + staging ----
        if (q == 2) {
            float a0=0.f,a1=0.f,a2=0.f,a3=0.f;
            const float4* h4 = (const float4*)hs;
            #pragma unroll
            for (int i = 0; i < 16; ++i) {
                float4 hv = h4[i];
                a0 = fmaf(wv[4*i+0], hv.x, a0);
                a1 = fmaf(wv[4*i+1], hv.y, a1);
                a2 = fmaf(wv[4*i+2], hv.z, a2);
                a3 = fmaf(wv[4*i+3], hv.w, a3);
            }
            phs[g] = (a0 + a1) + (a2 + a3) + bh;
        } else if (MODE == 0) {
            if (q == 0) {
                p0s[g] = fmaf(w0, c0, bi);
                if (t + 2 < LSEQ) c2 = xp[prow(t + 2)];
            }
        } else {
            const float4* x4 = (const float4*)(&xs[t & 1][q * 64]);
            float a0=0.f,a1=0.f,a2=0.f,a3=0.f;
            #pragma unroll
            for (int i = 0; i < 16; ++i) {
                float4 xv = x4[i];
                a0 = fmaf(wv[4*i+0], xv.x, a0);
                a1 = fmaf(wv[4*i+1], xv.y, a1);
                a2 = fmaf(wv[4*i+2], xv.z, a2);
                a3 = fmaf(wv[4*i+3], xv.w, a3);
            }
            float s = (a0 + a1) + (a2 + a3);
            if (q == 0) p0s[g] = s + bi;
            else        p1s[g] = s;
            if (q == 1 && g < 64) {   // stage next row, prefetch t+2
                if (t + 1 < LSEQ) {
                    xs[(t+1) & 1][2*g]   = bf2f((u16)pf);
                    xs[(t+1) & 1][2*g+1] = bf2f((u16)(pf >> 16));
                }
                if (t + 2 < LSEQ)
                    pf = ((const u32*)(xb + (size_t)prow(t + 2) * 128))[g];
            }
        }
        __syncthreads();

        // ---- phase B: all three gates + h update, in-thread (wave 0) ----
        if (tid < HID) {
            const int j = tid;
            const float gr = p0s[j]       + p1s[j]       + phs[j];
            const float gz = p0s[64 + j]  + p1s[64 + j]  + phs[64 + j];
            const float gn = p0s[128 + j] + p1s[128 + j];
            const float r = 1.f / (1.f + __expf(-gr));
            const float z = 1.f / (1.f + __expf(-gz));
            float y = fmaf(r, phs[128 + j], gn);
            y = fminf(fmaxf(y, -15.f), 15.f);
            const float e = __expf(-2.f * y);
            const float n = (1.f - e) / (1.f + e);       // tanh(y)
            const float hn = fmaf(z, hs[j] - n, n);      // (1-z)*n + z*h
            hs[j] = hn;
            if (MODE <= 1) {
                lout[((size_t)bc * LSEQ + p) * 128 + d * HID + j] = f2bf(hn);
            } else if (p == LSEQ - 1) {
                lastb[(size_t)(bbase + bc) * 128 + d * HID + j] = hn;
            }
        }
        __syncthreads();

        // last layer, reverse dir: only t==0 (p==L-1) feeds the FC — stop.
        if (MODE == 2 && d == 1) return;
        if (MODE == 0) { c0 = c1; c1 = c2; }
    }
}

// ---------------------------------------------------------------------------
// FC, SINGLE block (lastb aliases d_out[0:16384] — stage to LDS first).
// ---------------------------------------------------------------------------
__global__ __launch_bounds__(1024) void fc_single(
    const float* __restrict__ fcw,
    const float* __restrict__ fcb,
    float* __restrict__ out)           // == lastb
{
    __shared__ float ls[128 * 128];    // 64 KiB
    for (int i = threadIdx.x; i < 128 * 128; i += 1024) ls[i] = out[i];
    __syncthreads();
    for (int idx = threadIdx.x; idx < 128 * NCLS; idx += 1024) {
        const int b = idx / NCLS;
        const int c = idx % NCLS;
        const float4* w4 = (const float4*)(fcw + (size_t)c * 128);
        const float4* l4 = (const float4*)(ls + b * 128);
        float acc = fcb[c];
        #pragma unroll
        for (int i = 0; i < 32; ++i) {
            float4 w = w4[i], l = l4[i];
            acc += w.x*l.x + w.y*l.y + w.z*l.z + w.w*l.w;
        }
        out[idx] = acc;
    }
}

// ---------------------------------------------------------------------------
// Workspace: two bf16 ping-pong activation buffers (lastb lives in d_out).
// r8 counters: Bc=128 selected => ws_size >= 256 MiB (full batch, 1 chunk).
// Ladder kept for safety.
// ---------------------------------------------------------------------------
extern "C" void kernel_launch(void* const* d_in, const int* in_sizes, int n_in,
                              void* d_out, int out_size, void* d_ws, size_t ws_size,
                              hipStream_t stream)
{
    if (n_in < 8) return;
    const float* x    = (const float*)d_in[0];   // [128][1][4096]
    const float* wih0 = (const float*)d_in[1];   // [2][192][1]
    const float* wih  = (const float*)d_in[2];   // [3][2][192][128]
    const float* whh  = (const float*)d_in[3];   // [4][2][192][64]
    const float* bih  = (const float*)d_in[4];   // [4][2][192]
    const float* bhh  = (const float*)d_in[5];   // [4][2][192]
    const float* fcw  = (const float*)d_in[6];   // [230][128]
    const float* fcb  = (const float*)d_in[7];   // [230]
    float* out   = (float*)d_out;
    float* lastb = out;                          // first 16384 floats of d_out

    const size_t seqb = (size_t)LSEQ * 128 * 2;  // 1 MiB per batch elem (bf16)
    int Bc = 0;
    {
        const int cand[] = {128, 96, 64, 48, 32, 24, 16, 12, 8, 4, 2, 1};
        for (int i = 0; i < 12; ++i)
            if (2ull * cand[i] * seqb <= ws_size) { Bc = cand[i]; break; }
    }
    if (Bc == 0) return;

    u16* bufA = (u16*)d_ws;
    u16* bufB = bufA + (size_t)Bc * LSEQ * 128;

    for (int bb = 0; bb < 128; ) {
        const int cur = (Bc < 128 - bb) ? Bc : (128 - bb);
        const float* xc = x + (size_t)bb * LSEQ;
        rec2b<0><<<2*cur, 576, 0, stream>>>(xc,   wih0,        bih,        whh,          bhh,        bufA, nullptr, bb);
        rec2b<1><<<2*cur, 576, 0, stream>>>(bufA, wih,         bih + 384,  whh + 24576,  bhh + 384,  bufB, nullptr, bb);
        rec2b<1><<<2*cur, 576, 0, stream>>>(bufB, wih + 49152, bih + 768,  whh + 49152,  bhh + 768,  bufA, nullptr, bb);
        rec2b<2><<<2*cur, 576, 0, stream>>>(bufA, wih + 98304, bih + 1152, whh + 73728,  bhh + 1152, nullptr, lastb, bb);
        bb += cur;
    }
    fc_single<<<1, 1024, 0, stream>>>(fcw, fcb, out);
}